// Round 5
// baseline (491.955 us; speedup 1.0000x reference)
//
#include <hip/hip_runtime.h>
#include <hip/hip_bf16.h>
#include <math.h>

#define D 128
#define BSHIFT 9          // bucket = id >> 9  (512 nodes/bucket)
#define NBUCK 256         // max buckets (N <= 131072)
#define EPB 2048          // edges per binning block (graph edges)
#define BCAP 7168         // bucket capacity (mean 6250, sigma 79 -> 11.6 sigma)
#define EPBQ 2048         // query edges per binning block
#define QCAP 2048         // query bucket capacity (mean ~1342, 19 sigma)
#define QSUB 8            // sub-blocks per query bucket in mlp_sorted
#define ESUB 4            // sub-blocks per bucket in ell build

typedef short s8v __attribute__((ext_vector_type(8)));
typedef float f4v __attribute__((ext_vector_type(4)));
typedef float f2v __attribute__((ext_vector_type(2)));

__device__ inline unsigned short f2bf(float f) {
    unsigned int u = __float_as_uint(f);
    return (unsigned short)((u + 0x7fffu + ((u >> 16) & 1u)) >> 16);
}
__device__ inline unsigned int pack2bf(float a, float b) {
    return (unsigned int)f2bf(a) | ((unsigned int)f2bf(b) << 16);
}
__device__ inline float bflo(unsigned int v) { return __uint_as_float(v << 16); }
__device__ inline float bfhi(unsigned int v) { return __uint_as_float(v & 0xffff0000u); }

// ---------------------------------------------------------------------------
// Mega-prep kernel: one dispatch does (by blockIdx range)
//   [0, binB)              graph-edge bucket scatter (reg-cached edges)
//   [binB, +convxB)        fp32 x -> bf16 + fp8
//   [+convwB)              weight conversion (Wc / Wuv / W2b)
//   [+qB)                  query-edge bucket scatter (u-bucketed, packed u64)
// Scatter blocks preload their 8 edges/thread into REGISTERS so the global
// load latency is paid once, in parallel -- the per-thread serial chain is
// then just ~16 LDS atomics (R4: 62us was one 8192-edge block's serial chain).
// ---------------------------------------------------------------------------
__global__ __launch_bounds__(256) void prep_kernel(
    const int* __restrict__ src, const int* __restrict__ dst,
    int* __restrict__ cursor, unsigned long long* __restrict__ packed,
    int E, int binB,
    const float* __restrict__ x, unsigned short* __restrict__ xb,
    unsigned int* __restrict__ xf8, int n4, int convxB,
    const float* __restrict__ W0l, const float* __restrict__ W0r,
    const float* __restrict__ W1l, const float* __restrict__ W1r,
    const float* __restrict__ W2l, const float* __restrict__ W2r,
    const float* __restrict__ lpW1, const float* __restrict__ lpW2,
    unsigned short* __restrict__ Wc, unsigned short* __restrict__ Wuv,
    unsigned short* __restrict__ W2b, int convwB,
    const int* __restrict__ qrow, const int* __restrict__ qcol,
    int* __restrict__ qcur, unsigned long long* __restrict__ qpacked, int EQ)
{
    __shared__ int hist[NBUCK];
    __shared__ int lbase[NBUCK];
    __shared__ int lcur[NBUCK];
    int b = blockIdx.x;
    int t = threadIdx.x;

    if (b < binB) {
        // ---- graph edge scatter (8 edges/thread, reg-cached) ----
        hist[t] = 0;
        lcur[t] = 0;
        int myd[8], mys[8];
        int lo = b * EPB;
        #pragma unroll
        for (int k = 0; k < 8; ++k) {
            int e = lo + t + k * 256;
            bool ok = e < E;
            myd[k] = ok ? dst[e] : -1;
            mys[k] = ok ? src[e] : 0;
        }
        __syncthreads();
        #pragma unroll
        for (int k = 0; k < 8; ++k)
            if (myd[k] >= 0) atomicAdd(&hist[myd[k] >> BSHIFT], 1);
        __syncthreads();
        if (hist[t]) lbase[t] = t * BCAP + atomicAdd(&cursor[t], hist[t]);
        __syncthreads();
        #pragma unroll
        for (int k = 0; k < 8; ++k) {
            if (myd[k] >= 0) {
                int bk = myd[k] >> BSHIFT;
                int lr = atomicAdd(&lcur[bk], 1);
                int pos = lbase[bk] + lr;
                if (pos < (bk + 1) * BCAP)   // overflow guard (P ~ 0)
                    packed[pos] = ((unsigned long long)(unsigned)myd[k] << 32) | (unsigned)mys[k];
            }
        }
        return;
    }
    b -= binB;
    if (b < convxB) {
        int i = b * 256 + t;
        if (i < n4) {
            float4 v = reinterpret_cast<const float4*>(x)[i];
            uint2 o;
            o.x = pack2bf(v.x, v.y);
            o.y = pack2bf(v.z, v.w);
            reinterpret_cast<uint2*>(xb)[i] = o;
            int p8 = __builtin_amdgcn_cvt_pk_fp8_f32(v.x, v.y, 0, false);
            p8 = __builtin_amdgcn_cvt_pk_fp8_f32(v.z, v.w, p8, true);
            xf8[i] = (unsigned int)p8;
        }
        return;
    }
    b -= convxB;
    if (b < convwB) {
        int idx = b * 256 + t;
        if (idx < 98304) {
            int layer = idx >> 15;
            int rem = idx & 32767;
            int r = rem >> 8;
            int c = rem & 255;
            const float* Wl = layer == 0 ? W0l : layer == 1 ? W1l : W2l;
            const float* Wr = layer == 0 ? W0r : layer == 1 ? W1r : W2r;
            float v = (c < 128) ? Wl[r * 128 + c] : Wr[r * 128 + (c - 128)];
            Wc[idx] = f2bf(v);
        } else if (idx < 131072) {
            int i = idx - 98304;
            int r = i >> 7;
            int c = i & 127;
            float v = (r < 128) ? lpW1[r * 256 + c] : lpW1[(r - 128) * 256 + 128 + c];
            Wuv[i] = f2bf(v);
        } else if (idx < 131072 + 8192) {
            int i = idx - 131072;
            W2b[i] = f2bf(lpW2[i]);
        }
        return;
    }
    b -= convwB;
    {
        // ---- query edge scatter (8 edges/thread, reg-cached) ----
        hist[t] = 0;
        lcur[t] = 0;
        int myu[8], myc[8];
        int lo = b * EPBQ;
        #pragma unroll
        for (int k = 0; k < 8; ++k) {
            int e = lo + t + k * 256;
            bool ok = e < EQ;
            myu[k] = ok ? qrow[e] : -1;
            myc[k] = ok ? qcol[e] : 0;
        }
        __syncthreads();
        #pragma unroll
        for (int k = 0; k < 8; ++k)
            if (myu[k] >= 0) atomicAdd(&hist[myu[k] >> BSHIFT], 1);
        __syncthreads();
        if (hist[t]) lbase[t] = t * QCAP + atomicAdd(&qcur[t], hist[t]);
        __syncthreads();
        #pragma unroll
        for (int k = 0; k < 8; ++k) {
            if (myu[k] >= 0) {
                int e = lo + t + k * 256;
                int bk = myu[k] >> BSHIFT;
                int lr = atomicAdd(&lcur[bk], 1);
                int pos = lbase[bk] + lr;
                if (pos < (bk + 1) * QCAP)
                    qpacked[pos] = ((unsigned long long)(unsigned)myu[k] << 40)
                                 | ((unsigned long long)(unsigned)myc[k] << 20)
                                 | (unsigned)e;
            }
        }
    }
}

// ---------------------------------------------------------------------------
// ELL build: ESUB sub-blocks per bucket (shorter atomic chains, 4x blocks).
// cnt/ell slabs for a bucket stay L2-resident; order within a bucket is
// nondeterministic (was already -- mean is order-tolerant).
// ---------------------------------------------------------------------------
__global__ __launch_bounds__(256) void ell_from_sorted_kernel(
    const unsigned long long* __restrict__ packed, const int* __restrict__ cursor,
    int* __restrict__ cnt, int* __restrict__ ell)
{
    int b = blockIdx.x >> 2;
    int sub = blockIdx.x & (ESUB - 1);
    int lo = b * BCAP;
    int hi = lo + cursor[b];            // cursor is RELATIVE count
    for (int e = lo + sub * 256 + threadIdx.x; e < hi; e += 256 * ESUB) {
        unsigned long long p = packed[e];
        int d = (int)(p >> 32);
        int s = (int)(p & 0xffffffffu);
        int pos = atomicAdd(&cnt[d], 1);
        if (pos < 64) ell[((size_t)d << 6) + pos] = s;
    }
}

// ---------------------------------------------------------------------------
// Gather-mean kernel: 16-lane group owns whole nodes, lane c owns cols
// 8c..8c+7 (no cross-lane reduce). ~85% of the random-access fabric floor.
// ---------------------------------------------------------------------------
__global__ __launch_bounds__(256, 4) void gather_mean_kernel(
    const uint2* __restrict__ x8, const int* __restrict__ cnt,
    const int* __restrict__ ell, unsigned short* __restrict__ mb, int N)
{
    int t = threadIdx.x;
    int lane = t & 15;           // lane within group
    int grp = t >> 4;            // group within block
    int nb = blockIdx.x * 64 + grp * 4;

    #pragma unroll 2
    for (int i = 0; i < 4; ++i) {
        int n = nb + i;
        bool valid = n < N;
        int deg = valid ? cnt[n] : 0;
        int degc = min(deg, 64);
        float acc[8] = {0.f, 0.f, 0.f, 0.f, 0.f, 0.f, 0.f, 0.f};
        for (int base = 0; base < degc; base += 16) {
            int idx = ell[((size_t)n << 6) + base + lane];
            #pragma unroll
            for (int e = 0; e < 16; ++e) {
                int id = __shfl(idx, e, 16);
                bool ok = (base + e) < degc;
                float wt = ok ? 1.0f : 0.0f;
                uint2 v = x8[(size_t)(ok ? id : 0) * 16 + lane];
                f2v f0 = __builtin_amdgcn_cvt_pk_f32_fp8((int)v.x, false);
                f2v f1 = __builtin_amdgcn_cvt_pk_f32_fp8((int)v.x, true);
                f2v g0 = __builtin_amdgcn_cvt_pk_f32_fp8((int)v.y, false);
                f2v g1 = __builtin_amdgcn_cvt_pk_f32_fp8((int)v.y, true);
                acc[0] += wt * f0.x;  acc[1] += wt * f0.y;
                acc[2] += wt * f1.x;  acc[3] += wt * f1.y;
                acc[4] += wt * g0.x;  acc[5] += wt * g0.y;
                acc[6] += wt * g1.x;  acc[7] += wt * g1.y;
            }
        }
        if (valid) {
            float inv = 1.0f / fmaxf((float)deg, 1.0f);
            uint4 o;
            unsigned int* po = reinterpret_cast<unsigned int*>(&o);
            #pragma unroll
            for (int dd = 0; dd < 4; ++dd)
                po[dd] = pack2bf(acc[2 * dd] * inv, acc[2 * dd + 1] * inv);
            *reinterpret_cast<uint4*>(mb + (size_t)n * D + lane * 8) = o;
        }
    }
}

// ---------------------------------------------------------------------------
// SAGE GEMM layer (64 nodes/block): stage mean+self coalesced, K=256 MFMA
// GEMM (B register-cached), cross-wave L2-norm, relu, bf16 store + fp8
// epilogue (bit-identical to the old conv8 pass).
// mb/xout may alias (in-place): block reads its own rows before writing them.
// ---------------------------------------------------------------------------
__global__ __launch_bounds__(256) void sage_gemm_kernel(
    const unsigned short* __restrict__ xs, const unsigned short* mb,
    const unsigned short* __restrict__ Wc, const float* __restrict__ bl,
    unsigned short* xout, unsigned short* __restrict__ f8out, int N)
{
    __shared__ unsigned short sA[64][264];
    __shared__ float sNorm[4][64];

    int t = threadIdx.x;
    int lane = t & 63;
    int w = t >> 6;
    int n0 = blockIdx.x * 64;
    const uint4* x4 = reinterpret_cast<const uint4*>(xs);
    const uint4* m4 = reinterpret_cast<const uint4*>(mb);

    #pragma unroll
    for (int i = 0; i < 8; ++i) {
        int flat = i * 256 + t;
        int row = flat >> 5;
        int sub = flat & 31;
        int n = n0 + row;
        uint4 v = {0u, 0u, 0u, 0u};
        if (n < N)
            v = (sub < 16) ? m4[(size_t)n * 16 + sub] : x4[(size_t)n * 16 + (sub - 16)];
        *reinterpret_cast<uint4*>(&sA[row][sub * 8]) = v;
    }

    int n16 = lane & 15;
    int q = lane >> 4;

    s8v bfrag[8][2];
    #pragma unroll
    for (int j = 0; j < 2; ++j) {
        const s8v* Brow = reinterpret_cast<const s8v*>(Wc + (size_t)(w * 32 + j * 16 + n16) * 256);
        #pragma unroll
        for (int s = 0; s < 8; ++s) bfrag[s][j] = Brow[s * 4 + q];
    }
    __syncthreads();

    f4v acc[4][2];
    #pragma unroll
    for (int m = 0; m < 4; ++m) {
        acc[m][0] = f4v{0.0f, 0.0f, 0.0f, 0.0f};
        acc[m][1] = f4v{0.0f, 0.0f, 0.0f, 0.0f};
    }
    #pragma unroll
    for (int m = 0; m < 4; ++m) {
        const s8v* Arow = reinterpret_cast<const s8v*>(&sA[m * 16 + n16][0]);
        #pragma unroll
        for (int s = 0; s < 8; ++s) {
            s8v a = Arow[s * 4 + q];
            acc[m][0] = __builtin_amdgcn_mfma_f32_16x16x32_bf16(a, bfrag[s][0], acc[m][0], 0, 0, 0);
            acc[m][1] = __builtin_amdgcn_mfma_f32_16x16x32_bf16(a, bfrag[s][1], acc[m][1], 0, 0, 0);
        }
    }

    float bj0 = bl[w * 32 + n16];
    float bj1 = bl[w * 32 + 16 + n16];
    #pragma unroll
    for (int m = 0; m < 4; ++m) {
        #pragma unroll
        for (int r = 0; r < 4; ++r) { acc[m][0][r] += bj0; acc[m][1][r] += bj1; }
    }

    #pragma unroll
    for (int m = 0; m < 4; ++m) {
        float p[4];
        #pragma unroll
        for (int r = 0; r < 4; ++r)
            p[r] = acc[m][0][r] * acc[m][0][r] + acc[m][1][r] * acc[m][1][r];
        #pragma unroll
        for (int off = 1; off <= 8; off <<= 1) {
            #pragma unroll
            for (int r = 0; r < 4; ++r) p[r] += __shfl_xor(p[r], off, 64);
        }
        if (n16 == 0) {
            #pragma unroll
            for (int r = 0; r < 4; ++r) sNorm[w][m * 16 + q * 4 + r] = p[r];
        }
    }
    __syncthreads();

    #pragma unroll
    for (int m = 0; m < 4; ++m) {
        #pragma unroll
        for (int r = 0; r < 4; ++r) {
            int node = m * 16 + q * 4 + r;
            int n = n0 + node;
            if (n < N) {
                float tot = sNorm[0][node] + sNorm[1][node] + sNorm[2][node] + sNorm[3][node];
                float scl = 1.0f / fmaxf(sqrtf(tot), 1e-12f);
                unsigned short h0 = f2bf(fmaxf(acc[m][0][r] * scl, 0.0f));
                unsigned short h1 = f2bf(fmaxf(acc[m][1][r] * scl, 0.0f));
                xout[(size_t)n * D + w * 32 + n16]      = h0;
                xout[(size_t)n * D + w * 32 + 16 + n16] = h1;
                // fp8 epilogue (bit-identical to conv8 of the stored bf16)
                float y0 = __uint_as_float((unsigned int)h0 << 16);
                float y1 = __uint_as_float((unsigned int)h1 << 16);
                float z0 = __shfl_xor(y0, 1, 64);
                float z1 = __shfl_xor(y1, 1, 64);
                if ((n16 & 1) == 0) {
                    int pk0 = __builtin_amdgcn_cvt_pk_fp8_f32(y0, z0, 0, false);
                    int pk1 = __builtin_amdgcn_cvt_pk_fp8_f32(y1, z1, 0, false);
                    f8out[(size_t)n * 64 + w * 16 + (n16 >> 1)]     = (unsigned short)pk0;
                    f8out[(size_t)n * 64 + w * 16 + 8 + (n16 >> 1)] = (unsigned short)pk1;
                }
            }
        }
    }
}

// ---------------------------------------------------------------------------
// SAGE GEMM layer 3 + uv
// ---------------------------------------------------------------------------
__global__ __launch_bounds__(256) void sage_gemm_uv_kernel(
    const unsigned short* __restrict__ xs, const unsigned short* __restrict__ mb,
    const unsigned short* __restrict__ Wc, const float* __restrict__ bl,
    const unsigned short* __restrict__ Wuv, const float* __restrict__ lpb1,
    unsigned short* __restrict__ uv, int N)
{
    __shared__ unsigned short sA[64][264];
    __shared__ float sNorm[4][64];

    int t = threadIdx.x;
    int lane = t & 63;
    int w = t >> 6;
    int n0 = blockIdx.x * 64;
    const uint4* x4 = reinterpret_cast<const uint4*>(xs);
    const uint4* m4 = reinterpret_cast<const uint4*>(mb);

    #pragma unroll
    for (int i = 0; i < 8; ++i) {
        int flat = i * 256 + t;
        int row = flat >> 5;
        int sub = flat & 31;
        int n = n0 + row;
        uint4 v = {0u, 0u, 0u, 0u};
        if (n < N)
            v = (sub < 16) ? m4[(size_t)n * 16 + sub] : x4[(size_t)n * 16 + (sub - 16)];
        *reinterpret_cast<uint4*>(&sA[row][sub * 8]) = v;
    }

    int n16 = lane & 15;
    int q = lane >> 4;

    s8v bfrag[8][2];
    #pragma unroll
    for (int j = 0; j < 2; ++j) {
        const s8v* Brow = reinterpret_cast<const s8v*>(Wc + (size_t)(w * 32 + j * 16 + n16) * 256);
        #pragma unroll
        for (int s = 0; s < 8; ++s) bfrag[s][j] = Brow[s * 4 + q];
    }
    __syncthreads();

    f4v acc[4][2];
    #pragma unroll
    for (int m = 0; m < 4; ++m) {
        acc[m][0] = f4v{0.0f, 0.0f, 0.0f, 0.0f};
        acc[m][1] = f4v{0.0f, 0.0f, 0.0f, 0.0f};
    }
    #pragma unroll
    for (int m = 0; m < 4; ++m) {
        const s8v* Arow = reinterpret_cast<const s8v*>(&sA[m * 16 + n16][0]);
        #pragma unroll
        for (int s = 0; s < 8; ++s) {
            s8v a = Arow[s * 4 + q];
            acc[m][0] = __builtin_amdgcn_mfma_f32_16x16x32_bf16(a, bfrag[s][0], acc[m][0], 0, 0, 0);
            acc[m][1] = __builtin_amdgcn_mfma_f32_16x16x32_bf16(a, bfrag[s][1], acc[m][1], 0, 0, 0);
        }
    }

    float bj0 = bl[w * 32 + n16];
    float bj1 = bl[w * 32 + 16 + n16];
    #pragma unroll
    for (int m = 0; m < 4; ++m) {
        #pragma unroll
        for (int r = 0; r < 4; ++r) { acc[m][0][r] += bj0; acc[m][1][r] += bj1; }
    }

    #pragma unroll
    for (int m = 0; m < 4; ++m) {
        float p[4];
        #pragma unroll
        for (int r = 0; r < 4; ++r)
            p[r] = acc[m][0][r] * acc[m][0][r] + acc[m][1][r] * acc[m][1][r];
        #pragma unroll
        for (int off = 1; off <= 8; off <<= 1) {
            #pragma unroll
            for (int r = 0; r < 4; ++r) p[r] += __shfl_xor(p[r], off, 64);
        }
        if (n16 == 0) {
            #pragma unroll
            for (int r = 0; r < 4; ++r) sNorm[w][m * 16 + q * 4 + r] = p[r];
        }
    }
    __syncthreads();

    #pragma unroll
    for (int m = 0; m < 4; ++m) {
        #pragma unroll
        for (int r = 0; r < 4; ++r) {
            int node = m * 16 + q * 4 + r;
            float tot = sNorm[0][node] + sNorm[1][node] + sNorm[2][node] + sNorm[3][node];
            float scl = 1.0f / fmaxf(sqrtf(tot), 1e-12f);
            sA[node][w * 32 + n16]      = f2bf(fmaxf(acc[m][0][r] * scl, 0.0f));
            sA[node][w * 32 + 16 + n16] = f2bf(fmaxf(acc[m][1][r] * scl, 0.0f));
        }
    }

    s8v ufrag[4][4];
    float ubj[4];
    #pragma unroll
    for (int j = 0; j < 4; ++j) {
        int col = w * 64 + j * 16 + n16;
        const s8v* Brow = reinterpret_cast<const s8v*>(Wuv + (size_t)col * 128);
        #pragma unroll
        for (int s = 0; s < 4; ++s) ufrag[j][s] = Brow[s * 4 + q];
        ubj[j] = (col < 128) ? lpb1[col] : 0.0f;
    }
    __syncthreads();

    #pragma unroll
    for (int m = 0; m < 4; ++m) {
        f4v ua[4];
        #pragma unroll
        for (int j = 0; j < 4; ++j) ua[j] = f4v{0.0f, 0.0f, 0.0f, 0.0f};
        const s8v* Arow = reinterpret_cast<const s8v*>(&sA[m * 16 + n16][0]);
        #pragma unroll
        for (int s = 0; s < 4; ++s) {
            s8v a = Arow[s * 4 + q];
            #pragma unroll
            for (int j = 0; j < 4; ++j)
                ua[j] = __builtin_amdgcn_mfma_f32_16x16x32_bf16(a, ufrag[j][s], ua[j], 0, 0, 0);
        }
        #pragma unroll
        for (int r = 0; r < 4; ++r) {
            int n = n0 + m * 16 + q * 4 + r;
            if (n < N) {
                #pragma unroll
                for (int j = 0; j < 4; ++j)
                    uv[(size_t)n * 256 + w * 64 + j * 16 + n16] = f2bf(ua[j][r] + ubj[j]);
            }
        }
    }
}

// ---------------------------------------------------------------------------
// Edge MLP, u-bucket-sorted: grid = NBUCK x QSUB.
// ---------------------------------------------------------------------------
__global__ __launch_bounds__(256) void mlp_sorted_kernel(
    const unsigned short* __restrict__ uv, const unsigned long long* __restrict__ qpacked,
    const int* __restrict__ qcur, const unsigned short* __restrict__ W2b,
    const float* __restrict__ lpb2, const float* __restrict__ lpW3,
    const float* __restrict__ lpb3, float* __restrict__ out)
{
    int b = blockIdx.x >> 3;
    int sub = blockIdx.x & (QSUB - 1);
    int qn = min(qcur[b], QCAP);
    if (qn <= 0) return;
    int qbase = b * QCAP;
    int tiles = (qn + 63) >> 6;

    int t = threadIdx.x;
    int lane = t & 63;
    int w = t >> 6;
    int n16 = lane & 15;
    int q = lane >> 4;
    const uint4* uv4 = reinterpret_cast<const uint4*>(uv);
    float b3 = lpb3[0];

    for (int tile = sub; tile < tiles; tile += QSUB) {
        int k = tile * 64 + w * 16 + n16;
        int kc = min(k, qn - 1);
        unsigned long long p = qpacked[qbase + kc];
        int nr = (int)(p >> 40);
        int nc = (int)((p >> 20) & 0xFFFFFu);
        int eqi = (int)(p & 0xFFFFFu);

        uint4 uu[4], vv[4];
        #pragma unroll
        for (int s = 0; s < 4; ++s) uu[s] = uv4[(size_t)nr * 32 + s * 4 + q];
        #pragma unroll
        for (int s = 0; s < 4; ++s) vv[s] = uv4[(size_t)nc * 32 + 16 + s * 4 + q];

        s8v h[4];
        #pragma unroll
        for (int s = 0; s < 4; ++s) {
            const unsigned int* pu = reinterpret_cast<const unsigned int*>(&uu[s]);
            const unsigned int* pv = reinterpret_cast<const unsigned int*>(&vv[s]);
            union { unsigned int u[4]; s8v v; } tmp;
            #pragma unroll
            for (int d = 0; d < 4; ++d) {
                float lo = fmaxf(bflo(pu[d]) + bflo(pv[d]), 0.0f);
                float hi = fmaxf(bfhi(pu[d]) + bfhi(pv[d]), 0.0f);
                tmp.u[d] = pack2bf(lo, hi);
            }
            h[s] = tmp.v;
        }

        f4v acc[4];
        #pragma unroll
        for (int nt = 0; nt < 4; ++nt) acc[nt] = f4v{0.0f, 0.0f, 0.0f, 0.0f};
        for (int s = 0; s < 4; ++s) {
            #pragma unroll
            for (int nt = 0; nt < 4; ++nt) {
                const s8v* Brow = reinterpret_cast<const s8v*>(W2b + (size_t)(nt * 16 + n16) * 128);
                s8v bfr = Brow[s * 4 + q];
                acc[nt] = __builtin_amdgcn_mfma_f32_16x16x32_bf16(h[s], bfr, acc[nt], 0, 0, 0);
            }
        }

        float part[4] = {0.0f, 0.0f, 0.0f, 0.0f};
        #pragma unroll
        for (int nt = 0; nt < 4; ++nt) {
            float bj = lpb2[nt * 16 + n16];
            float w3 = lpW3[nt * 16 + n16];
            #pragma unroll
            for (int r = 0; r < 4; ++r) {
                float h2 = fmaxf(acc[nt][r] + bj, 0.0f);
                part[r] += h2 * w3;
            }
        }
        #pragma unroll
        for (int off = 1; off <= 8; off <<= 1) {
            #pragma unroll
            for (int r = 0; r < 4; ++r) part[r] += __shfl_xor(part[r], off, 64);
        }
        #pragma unroll
        for (int r = 0; r < 4; ++r) {
            int jj = q * 4 + r;
            int eqr = __shfl(eqi, jj, 16);       // executed by all lanes
            int slot = tile * 64 + w * 16 + jj;
            if (n16 == 0 && slot < qn) {
                float s = part[r] + b3;
                out[eqr] = 1.0f / (1.0f + expf(-s));
            }
        }
    }
}

// ---------------------------------------------------------------------------
// Plain edge MLP (fallback when workspace lacks qpacked room)
// ---------------------------------------------------------------------------
__global__ __launch_bounds__(256) void mlp_kernel(
    const unsigned short* __restrict__ uv, const int* __restrict__ rowI,
    const int* __restrict__ colI, const unsigned short* __restrict__ W2b,
    const float* __restrict__ lpb2, const float* __restrict__ lpW3,
    const float* __restrict__ lpb3, float* __restrict__ out, int EQ)
{
    int t = threadIdx.x;
    int lane = t & 63;
    int w = t >> 6;
    int n16 = lane & 15;
    int q = lane >> 4;
    int e = blockIdx.x * 64 + w * 16 + n16;
    int ec = min(e, EQ - 1);
    int nr = rowI[ec];
    int nc = colI[ec];
    const uint4* uv4 = reinterpret_cast<const uint4*>(uv);

    uint4 uu[4], vv[4];
    #pragma unroll
    for (int s = 0; s < 4; ++s) uu[s] = uv4[(size_t)nr * 32 + s * 4 + q];
    #pragma unroll
    for (int s = 0; s < 4; ++s) vv[s] = uv4[(size_t)nc * 32 + 16 + s * 4 + q];

    s8v h[4];
    #pragma unroll
    for (int s = 0; s < 4; ++s) {
        const unsigned int* pu = reinterpret_cast<const unsigned int*>(&uu[s]);
        const unsigned int* pv = reinterpret_cast<const unsigned int*>(&vv[s]);
        union { unsigned int u[4]; s8v v; } tmp;
        #pragma unroll
        for (int d = 0; d < 4; ++d) {
            float lo = fmaxf(bflo(pu[d]) + bflo(pv[d]), 0.0f);
            float hi = fmaxf(bfhi(pu[d]) + bfhi(pv[d]), 0.0f);
            tmp.u[d] = pack2bf(lo, hi);
        }
        h[s] = tmp.v;
    }

    f4v acc[4];
    #pragma unroll
    for (int nt = 0; nt < 4; ++nt) acc[nt] = f4v{0.0f, 0.0f, 0.0f, 0.0f};
    for (int s = 0; s < 4; ++s) {
        #pragma unroll
        for (int nt = 0; nt < 4; ++nt) {
            const s8v* Brow = reinterpret_cast<const s8v*>(W2b + (size_t)(nt * 16 + n16) * 128);
            s8v b = Brow[s * 4 + q];
            acc[nt] = __builtin_amdgcn_mfma_f32_16x16x32_bf16(h[s], b, acc[nt], 0, 0, 0);
        }
    }

    float part[4] = {0.0f, 0.0f, 0.0f, 0.0f};
    #pragma unroll
    for (int nt = 0; nt < 4; ++nt) {
        float bj = lpb2[nt * 16 + n16];
        float w3 = lpW3[nt * 16 + n16];
        #pragma unroll
        for (int r = 0; r < 4; ++r) {
            float h2 = fmaxf(acc[nt][r] + bj, 0.0f);
            part[r] += h2 * w3;
        }
    }
    #pragma unroll
    for (int off = 1; off <= 8; off <<= 1) {
        #pragma unroll
        for (int r = 0; r < 4; ++r) part[r] += __shfl_xor(part[r], off, 64);
    }
    if (n16 == 0) {
        float b3 = lpb3[0];
        #pragma unroll
        for (int r = 0; r < 4; ++r) {
            int eq = blockIdx.x * 64 + w * 16 + q * 4 + r;
            if (eq < EQ) {
                float s = part[r] + b3;
                out[eq] = 1.0f / (1.0f + expf(-s));
            }
        }
    }
}

// ---------------------------------------------------------------------------
extern "C" void kernel_launch(void* const* d_in, const int* in_sizes, int n_in,
                              void* d_out, int out_size, void* d_ws, size_t ws_size,
                              hipStream_t stream)
{
    const float* x   = (const float*)d_in[0];
    const int*   ei  = (const int*)d_in[1];
    const int*   eiq = (const int*)d_in[2];
    const float* Wl[3] = {(const float*)d_in[3], (const float*)d_in[6], (const float*)d_in[9]};
    const float* bl[3] = {(const float*)d_in[4], (const float*)d_in[7], (const float*)d_in[10]};
    const float* Wr[3] = {(const float*)d_in[5], (const float*)d_in[8], (const float*)d_in[11]};
    const float* lpW1 = (const float*)d_in[12];
    const float* lpb1 = (const float*)d_in[13];
    const float* lpW2 = (const float*)d_in[14];
    const float* lpb2 = (const float*)d_in[15];
    const float* lpW3 = (const float*)d_in[16];
    const float* lpb3 = (const float*)d_in[17];

    int N  = in_sizes[0] / D;
    int E  = in_sizes[1] / 2;
    int EQ = in_sizes[2] / 2;

    // ---- workspace layout (unchanged from R4) ----
    int* cnt    = (int*)d_ws;                    // N
    int* cursor = cnt + N;                       // NBUCK (relative counts)
    int* qcur   = cursor + NBUCK;                // NBUCK
    int* ell    = qcur + NBUCK;                  // N * 64
    size_t intWords = (size_t)N + 2 * NBUCK + (size_t)N * 64;
    intWords = (intWords + 15) & ~(size_t)15;
    size_t nd = (size_t)N * D;
    unsigned short* bufA = (unsigned short*)((int*)d_ws + intWords);
    unsigned short* bufB = bufA + nd;
    unsigned short* bufC = bufB + nd;
    unsigned int* f8a = (unsigned int*)(bufC + nd);   // nd/4 uints each
    unsigned int* f8b = f8a + nd / 4;
    unsigned int* f8c = f8b + nd / 4;
    unsigned long long* packed = (unsigned long long*)(f8c + nd / 4);
    unsigned short* Wc  = (unsigned short*)(packed + (size_t)NBUCK * BCAP);
    unsigned short* Wuv = Wc + 98304;
    unsigned short* W2b = Wuv + 32768;
    size_t qoff = (size_t)((char*)(W2b + 8192) - (char*)d_ws);
    qoff = (qoff + 7) & ~(size_t)7;
    unsigned long long* qpacked = (unsigned long long*)((char*)d_ws + qoff);
    size_t needQ = qoff + (size_t)NBUCK * QCAP * 8;
    int doQ = (ws_size >= needQ) ? 1 : 0;
    unsigned short* uvb = (unsigned short*)f8a;       // overlay

    const int* src = ei;
    const int* dst = ei + E;

    // ---- one memset for all counters, then the mega-prep dispatch ----
    hipMemsetAsync(cnt, 0, ((size_t)N + 2 * NBUCK) * sizeof(int), stream);
    int n4 = (int)(nd / 4);
    int binB   = (E + EPB - 1) / EPB;
    int convxB = (n4 + 255) / 256;
    int convwB = (139264 + 255) / 256;
    int qB     = doQ ? (EQ + EPBQ - 1) / EPBQ : 0;
    int prepGrid = binB + convxB + convwB + qB;
    prep_kernel<<<prepGrid, 256, 0, stream>>>(
        src, dst, cursor, packed, E, binB,
        x, bufA, f8a, n4, convxB,
        Wl[0], Wr[0], Wl[1], Wr[1], Wl[2], Wr[2], lpW1, lpW2, Wc, Wuv, W2b, convwB,
        eiq, eiq + EQ, qcur, qpacked, EQ);
    ell_from_sorted_kernel<<<NBUCK * ESUB, 256, 0, stream>>>(packed, cursor, cnt, ell);

    // ---- 3 SAGE layers: gather + GEMM (fp8 emitted in GEMM epilogue) ----
    int mBlocks = (N + 63) / 64;
    gather_mean_kernel<<<mBlocks, 256, 0, stream>>>(
        (const uint2*)f8a, cnt, ell, bufB, N);
    sage_gemm_kernel<<<mBlocks, 256, 0, stream>>>(
        bufA, bufB, Wc, bl[0], bufB, (unsigned short*)f8b, N);

    gather_mean_kernel<<<mBlocks, 256, 0, stream>>>(
        (const uint2*)f8b, cnt, ell, bufC, N);
    sage_gemm_kernel<<<mBlocks, 256, 0, stream>>>(
        bufB, bufC, Wc + 32768, bl[1], bufC, (unsigned short*)f8c, N);

    gather_mean_kernel<<<mBlocks, 256, 0, stream>>>(
        (const uint2*)f8c, cnt, ell, bufA, N);
    sage_gemm_uv_kernel<<<mBlocks, 256, 0, stream>>>(
        bufC, bufA, Wc + 65536, bl[2], Wuv, lpb1, uvb, N);

    // ---- edge MLP ----
    if (doQ) {
        mlp_sorted_kernel<<<NBUCK * QSUB, 256, 0, stream>>>(
            uvb, qpacked, qcur, W2b, lpb2, lpW3, lpb3, (float*)d_out);
    } else {
        mlp_kernel<<<(EQ + 63) / 64, 256, 0, stream>>>(
            uvb, eiq, eiq + EQ, W2b, lpb2, lpW3, lpb3, (float*)d_out, EQ);
    }
}

// Round 6
// 441.730 us; speedup vs baseline: 1.1137x; 1.1137x over previous
//
#include <hip/hip_runtime.h>
#include <hip/hip_bf16.h>
#include <math.h>

#define D 128
#define BSHIFT 9          // bucket = id >> 9  (512 nodes/bucket)
#define NBUCK 256         // max buckets (N <= 131072)
#define EPB 2048          // edges per binning block (graph edges)
#define BCAP 7168         // bucket capacity (mean 6250, sigma 79 -> 11.6 sigma)
#define EPBQ 2048         // query edges per binning block
#define QCAP 2048         // query bucket capacity (mean ~1342, 19 sigma)
#define QSUB 8            // sub-blocks per query bucket in mlp_sorted
#define ENPB 128          // nodes per ell-build block (1/4 bucket)

typedef short s8v __attribute__((ext_vector_type(8)));
typedef float f4v __attribute__((ext_vector_type(4)));
typedef float f2v __attribute__((ext_vector_type(2)));

__device__ inline unsigned short f2bf(float f) {
    unsigned int u = __float_as_uint(f);
    return (unsigned short)((u + 0x7fffu + ((u >> 16) & 1u)) >> 16);
}
__device__ inline unsigned int pack2bf(float a, float b) {
    return (unsigned int)f2bf(a) | ((unsigned int)f2bf(b) << 16);
}
__device__ inline float bflo(unsigned int v) { return __uint_as_float(v << 16); }
__device__ inline float bfhi(unsigned int v) { return __uint_as_float(v & 0xffff0000u); }

// ---------------------------------------------------------------------------
// Mega-prep kernel: one dispatch does (by blockIdx range)
//   [0, binB)              graph-edge bucket scatter (reg-cached edges)
//   [binB, +convxB)        fp32 x -> bf16 + fp8
//   [+convwB)              weight conversion (Wc / Wuv / W2b)
//   [+qB)                  query-edge bucket scatter (u-bucketed, packed u64)
// ---------------------------------------------------------------------------
__global__ __launch_bounds__(256) void prep_kernel(
    const int* __restrict__ src, const int* __restrict__ dst,
    int* __restrict__ cursor, unsigned long long* __restrict__ packed,
    int E, int binB,
    const float* __restrict__ x, unsigned short* __restrict__ xb,
    unsigned int* __restrict__ xf8, int n4, int convxB,
    const float* __restrict__ W0l, const float* __restrict__ W0r,
    const float* __restrict__ W1l, const float* __restrict__ W1r,
    const float* __restrict__ W2l, const float* __restrict__ W2r,
    const float* __restrict__ lpW1, const float* __restrict__ lpW2,
    unsigned short* __restrict__ Wc, unsigned short* __restrict__ Wuv,
    unsigned short* __restrict__ W2b, int convwB,
    const int* __restrict__ qrow, const int* __restrict__ qcol,
    int* __restrict__ qcur, unsigned long long* __restrict__ qpacked, int EQ)
{
    __shared__ int hist[NBUCK];
    __shared__ int lbase[NBUCK];
    __shared__ int lcur[NBUCK];
    int b = blockIdx.x;
    int t = threadIdx.x;

    if (b < binB) {
        // ---- graph edge scatter (8 edges/thread, reg-cached) ----
        hist[t] = 0;
        lcur[t] = 0;
        int myd[8], mys[8];
        int lo = b * EPB;
        #pragma unroll
        for (int k = 0; k < 8; ++k) {
            int e = lo + t + k * 256;
            bool ok = e < E;
            myd[k] = ok ? dst[e] : -1;
            mys[k] = ok ? src[e] : 0;
        }
        __syncthreads();
        #pragma unroll
        for (int k = 0; k < 8; ++k)
            if (myd[k] >= 0) atomicAdd(&hist[myd[k] >> BSHIFT], 1);
        __syncthreads();
        if (hist[t]) lbase[t] = t * BCAP + atomicAdd(&cursor[t], hist[t]);
        __syncthreads();
        #pragma unroll
        for (int k = 0; k < 8; ++k) {
            if (myd[k] >= 0) {
                int bk = myd[k] >> BSHIFT;
                int lr = atomicAdd(&lcur[bk], 1);
                int pos = lbase[bk] + lr;
                if (pos < (bk + 1) * BCAP)   // overflow guard (P ~ 0)
                    packed[pos] = ((unsigned long long)(unsigned)myd[k] << 32) | (unsigned)mys[k];
            }
        }
        return;
    }
    b -= binB;
    if (b < convxB) {
        int i = b * 256 + t;
        if (i < n4) {
            float4 v = reinterpret_cast<const float4*>(x)[i];
            uint2 o;
            o.x = pack2bf(v.x, v.y);
            o.y = pack2bf(v.z, v.w);
            reinterpret_cast<uint2*>(xb)[i] = o;
            int p8 = __builtin_amdgcn_cvt_pk_fp8_f32(v.x, v.y, 0, false);
            p8 = __builtin_amdgcn_cvt_pk_fp8_f32(v.z, v.w, p8, true);
            xf8[i] = (unsigned int)p8;
        }
        return;
    }
    b -= convxB;
    if (b < convwB) {
        int idx = b * 256 + t;
        if (idx < 98304) {
            int layer = idx >> 15;
            int rem = idx & 32767;
            int r = rem >> 8;
            int c = rem & 255;
            const float* Wl = layer == 0 ? W0l : layer == 1 ? W1l : W2l;
            const float* Wr = layer == 0 ? W0r : layer == 1 ? W1r : W2r;
            float v = (c < 128) ? Wl[r * 128 + c] : Wr[r * 128 + (c - 128)];
            Wc[idx] = f2bf(v);
        } else if (idx < 131072) {
            int i = idx - 98304;
            int r = i >> 7;
            int c = i & 127;
            float v = (r < 128) ? lpW1[r * 256 + c] : lpW1[(r - 128) * 256 + 128 + c];
            Wuv[i] = f2bf(v);
        } else if (idx < 131072 + 8192) {
            int i = idx - 131072;
            W2b[i] = f2bf(lpW2[i]);
        }
        return;
    }
    b -= convwB;
    {
        // ---- query edge scatter (8 edges/thread, reg-cached) ----
        hist[t] = 0;
        lcur[t] = 0;
        int myu[8], myc[8];
        int lo = b * EPBQ;
        #pragma unroll
        for (int k = 0; k < 8; ++k) {
            int e = lo + t + k * 256;
            bool ok = e < EQ;
            myu[k] = ok ? qrow[e] : -1;
            myc[k] = ok ? qcol[e] : 0;
        }
        __syncthreads();
        #pragma unroll
        for (int k = 0; k < 8; ++k)
            if (myu[k] >= 0) atomicAdd(&hist[myu[k] >> BSHIFT], 1);
        __syncthreads();
        if (hist[t]) lbase[t] = t * QCAP + atomicAdd(&qcur[t], hist[t]);
        __syncthreads();
        #pragma unroll
        for (int k = 0; k < 8; ++k) {
            if (myu[k] >= 0) {
                int e = lo + t + k * 256;
                int bk = myu[k] >> BSHIFT;
                int lr = atomicAdd(&lcur[bk], 1);
                int pos = lbase[bk] + lr;
                if (pos < (bk + 1) * QCAP)
                    qpacked[pos] = ((unsigned long long)(unsigned)myu[k] << 40)
                                 | ((unsigned long long)(unsigned)myc[k] << 20)
                                 | (unsigned)e;
            }
        }
    }
}

// ---------------------------------------------------------------------------
// ELL build in LDS (R6): block owns 128 nodes (1/4 bucket). Scans the bucket
// slab coalesced, inserts via LDS atomics (no global atomics), then writes
// its 32KB ELL slab + counts fully coalesced with EXCLUSIVE line ownership
// (R5's 78MB write amplification came from 4 XCDs dirtying shared lines).
// Unused ELL slots carry garbage -- gather masks them (never used as addr).
// ---------------------------------------------------------------------------
__global__ __launch_bounds__(256) void ell_build_kernel(
    const unsigned long long* __restrict__ packed, const int* __restrict__ cursor,
    int* __restrict__ cnt, int* __restrict__ ell, int N)
{
    __shared__ int slds[ENPB * 64];     // 32 KB ELL staging
    __shared__ int lcnt[ENPB];          // full per-node counts
    int b = blockIdx.x >> 2;            // bucket
    int sub = blockIdx.x & 3;
    int nlo = b * 512 + sub * ENPB;     // first node of this block's range
    int t = threadIdx.x;

    for (int i = t; i < ENPB; i += 256) lcnt[i] = 0;
    __syncthreads();

    int lo = b * BCAP;
    int hi = lo + min(cursor[b], BCAP);
    for (int e = lo + t; e < hi; e += 256) {
        unsigned long long p = packed[e];
        int d = (int)(p >> 32);
        unsigned r = (unsigned)(d - nlo);
        if (r < ENPB) {
            int pos = atomicAdd(&lcnt[r], 1);
            if (pos < 64) slds[((int)r << 6) + pos] = (int)(p & 0xffffffffu);
        }
    }
    __syncthreads();

    // coalesced writeout: 128 rows x 16 uint4
    for (int i = t; i < ENPB * 16; i += 256) {
        int row = i >> 4;
        int n = nlo + row;
        if (n < N)
            reinterpret_cast<uint4*>(ell + ((size_t)n << 6))[i & 15] =
                reinterpret_cast<const uint4*>(slds)[i];
    }
    for (int i = t; i < ENPB; i += 256) {
        int n = nlo + i;
        if (n < N) cnt[n] = lcnt[i];
    }
}

// ---------------------------------------------------------------------------
// Gather-mean kernel: 16-lane group owns whole nodes, lane c owns cols
// 8c..8c+7 (no cross-lane reduce). ~85% of the random-access fabric floor.
// ---------------------------------------------------------------------------
__global__ __launch_bounds__(256, 4) void gather_mean_kernel(
    const uint2* __restrict__ x8, const int* __restrict__ cnt,
    const int* __restrict__ ell, unsigned short* __restrict__ mb, int N)
{
    int t = threadIdx.x;
    int lane = t & 15;           // lane within group
    int grp = t >> 4;            // group within block
    int nb = blockIdx.x * 64 + grp * 4;

    #pragma unroll 2
    for (int i = 0; i < 4; ++i) {
        int n = nb + i;
        bool valid = n < N;
        int deg = valid ? cnt[n] : 0;
        int degc = min(deg, 64);
        float acc[8] = {0.f, 0.f, 0.f, 0.f, 0.f, 0.f, 0.f, 0.f};
        for (int base = 0; base < degc; base += 16) {
            int idx = ell[((size_t)n << 6) + base + lane];
            #pragma unroll
            for (int e = 0; e < 16; ++e) {
                int id = __shfl(idx, e, 16);
                bool ok = (base + e) < degc;
                float wt = ok ? 1.0f : 0.0f;
                uint2 v = x8[(size_t)(ok ? id : 0) * 16 + lane];
                f2v f0 = __builtin_amdgcn_cvt_pk_f32_fp8((int)v.x, false);
                f2v f1 = __builtin_amdgcn_cvt_pk_f32_fp8((int)v.x, true);
                f2v g0 = __builtin_amdgcn_cvt_pk_f32_fp8((int)v.y, false);
                f2v g1 = __builtin_amdgcn_cvt_pk_f32_fp8((int)v.y, true);
                acc[0] += wt * f0.x;  acc[1] += wt * f0.y;
                acc[2] += wt * f1.x;  acc[3] += wt * f1.y;
                acc[4] += wt * g0.x;  acc[5] += wt * g0.y;
                acc[6] += wt * g1.x;  acc[7] += wt * g1.y;
            }
        }
        if (valid) {
            float inv = 1.0f / fmaxf((float)deg, 1.0f);
            uint4 o;
            unsigned int* po = reinterpret_cast<unsigned int*>(&o);
            #pragma unroll
            for (int dd = 0; dd < 4; ++dd)
                po[dd] = pack2bf(acc[2 * dd] * inv, acc[2 * dd + 1] * inv);
            *reinterpret_cast<uint4*>(mb + (size_t)n * D + lane * 8) = o;
        }
    }
}

// ---------------------------------------------------------------------------
// SAGE GEMM layer (64 nodes/block): stage mean+self coalesced, K=256 MFMA
// GEMM (B register-cached), cross-wave L2-norm, relu, bf16 store + fp8
// epilogue (bit-identical to the old conv8 pass).
// mb/xout may alias (in-place): block reads its own rows before writing them.
// ---------------------------------------------------------------------------
__global__ __launch_bounds__(256) void sage_gemm_kernel(
    const unsigned short* __restrict__ xs, const unsigned short* mb,
    const unsigned short* __restrict__ Wc, const float* __restrict__ bl,
    unsigned short* xout, unsigned short* __restrict__ f8out, int N)
{
    __shared__ unsigned short sA[64][264];
    __shared__ float sNorm[4][64];

    int t = threadIdx.x;
    int lane = t & 63;
    int w = t >> 6;
    int n0 = blockIdx.x * 64;
    const uint4* x4 = reinterpret_cast<const uint4*>(xs);
    const uint4* m4 = reinterpret_cast<const uint4*>(mb);

    #pragma unroll
    for (int i = 0; i < 8; ++i) {
        int flat = i * 256 + t;
        int row = flat >> 5;
        int sub = flat & 31;
        int n = n0 + row;
        uint4 v = {0u, 0u, 0u, 0u};
        if (n < N)
            v = (sub < 16) ? m4[(size_t)n * 16 + sub] : x4[(size_t)n * 16 + (sub - 16)];
        *reinterpret_cast<uint4*>(&sA[row][sub * 8]) = v;
    }

    int n16 = lane & 15;
    int q = lane >> 4;

    s8v bfrag[8][2];
    #pragma unroll
    for (int j = 0; j < 2; ++j) {
        const s8v* Brow = reinterpret_cast<const s8v*>(Wc + (size_t)(w * 32 + j * 16 + n16) * 256);
        #pragma unroll
        for (int s = 0; s < 8; ++s) bfrag[s][j] = Brow[s * 4 + q];
    }
    __syncthreads();

    f4v acc[4][2];
    #pragma unroll
    for (int m = 0; m < 4; ++m) {
        acc[m][0] = f4v{0.0f, 0.0f, 0.0f, 0.0f};
        acc[m][1] = f4v{0.0f, 0.0f, 0.0f, 0.0f};
    }
    #pragma unroll
    for (int m = 0; m < 4; ++m) {
        const s8v* Arow = reinterpret_cast<const s8v*>(&sA[m * 16 + n16][0]);
        #pragma unroll
        for (int s = 0; s < 8; ++s) {
            s8v a = Arow[s * 4 + q];
            acc[m][0] = __builtin_amdgcn_mfma_f32_16x16x32_bf16(a, bfrag[s][0], acc[m][0], 0, 0, 0);
            acc[m][1] = __builtin_amdgcn_mfma_f32_16x16x32_bf16(a, bfrag[s][1], acc[m][1], 0, 0, 0);
        }
    }

    float bj0 = bl[w * 32 + n16];
    float bj1 = bl[w * 32 + 16 + n16];
    #pragma unroll
    for (int m = 0; m < 4; ++m) {
        #pragma unroll
        for (int r = 0; r < 4; ++r) { acc[m][0][r] += bj0; acc[m][1][r] += bj1; }
    }

    #pragma unroll
    for (int m = 0; m < 4; ++m) {
        float p[4];
        #pragma unroll
        for (int r = 0; r < 4; ++r)
            p[r] = acc[m][0][r] * acc[m][0][r] + acc[m][1][r] * acc[m][1][r];
        #pragma unroll
        for (int off = 1; off <= 8; off <<= 1) {
            #pragma unroll
            for (int r = 0; r < 4; ++r) p[r] += __shfl_xor(p[r], off, 64);
        }
        if (n16 == 0) {
            #pragma unroll
            for (int r = 0; r < 4; ++r) sNorm[w][m * 16 + q * 4 + r] = p[r];
        }
    }
    __syncthreads();

    #pragma unroll
    for (int m = 0; m < 4; ++m) {
        #pragma unroll
        for (int r = 0; r < 4; ++r) {
            int node = m * 16 + q * 4 + r;
            int n = n0 + node;
            if (n < N) {
                float tot = sNorm[0][node] + sNorm[1][node] + sNorm[2][node] + sNorm[3][node];
                float scl = 1.0f / fmaxf(sqrtf(tot), 1e-12f);
                unsigned short h0 = f2bf(fmaxf(acc[m][0][r] * scl, 0.0f));
                unsigned short h1 = f2bf(fmaxf(acc[m][1][r] * scl, 0.0f));
                xout[(size_t)n * D + w * 32 + n16]      = h0;
                xout[(size_t)n * D + w * 32 + 16 + n16] = h1;
                // fp8 epilogue (bit-identical to conv8 of the stored bf16)
                float y0 = __uint_as_float((unsigned int)h0 << 16);
                float y1 = __uint_as_float((unsigned int)h1 << 16);
                float z0 = __shfl_xor(y0, 1, 64);
                float z1 = __shfl_xor(y1, 1, 64);
                if ((n16 & 1) == 0) {
                    int pk0 = __builtin_amdgcn_cvt_pk_fp8_f32(y0, z0, 0, false);
                    int pk1 = __builtin_amdgcn_cvt_pk_fp8_f32(y1, z1, 0, false);
                    f8out[(size_t)n * 64 + w * 16 + (n16 >> 1)]     = (unsigned short)pk0;
                    f8out[(size_t)n * 64 + w * 16 + 8 + (n16 >> 1)] = (unsigned short)pk1;
                }
            }
        }
    }
}

// ---------------------------------------------------------------------------
// SAGE GEMM layer 3 + uv
// ---------------------------------------------------------------------------
__global__ __launch_bounds__(256) void sage_gemm_uv_kernel(
    const unsigned short* __restrict__ xs, const unsigned short* __restrict__ mb,
    const unsigned short* __restrict__ Wc, const float* __restrict__ bl,
    const unsigned short* __restrict__ Wuv, const float* __restrict__ lpb1,
    unsigned short* __restrict__ uv, int N)
{
    __shared__ unsigned short sA[64][264];
    __shared__ float sNorm[4][64];

    int t = threadIdx.x;
    int lane = t & 63;
    int w = t >> 6;
    int n0 = blockIdx.x * 64;
    const uint4* x4 = reinterpret_cast<const uint4*>(xs);
    const uint4* m4 = reinterpret_cast<const uint4*>(mb);

    #pragma unroll
    for (int i = 0; i < 8; ++i) {
        int flat = i * 256 + t;
        int row = flat >> 5;
        int sub = flat & 31;
        int n = n0 + row;
        uint4 v = {0u, 0u, 0u, 0u};
        if (n < N)
            v = (sub < 16) ? m4[(size_t)n * 16 + sub] : x4[(size_t)n * 16 + (sub - 16)];
        *reinterpret_cast<uint4*>(&sA[row][sub * 8]) = v;
    }

    int n16 = lane & 15;
    int q = lane >> 4;

    s8v bfrag[8][2];
    #pragma unroll
    for (int j = 0; j < 2; ++j) {
        const s8v* Brow = reinterpret_cast<const s8v*>(Wc + (size_t)(w * 32 + j * 16 + n16) * 256);
        #pragma unroll
        for (int s = 0; s < 8; ++s) bfrag[s][j] = Brow[s * 4 + q];
    }
    __syncthreads();

    f4v acc[4][2];
    #pragma unroll
    for (int m = 0; m < 4; ++m) {
        acc[m][0] = f4v{0.0f, 0.0f, 0.0f, 0.0f};
        acc[m][1] = f4v{0.0f, 0.0f, 0.0f, 0.0f};
    }
    #pragma unroll
    for (int m = 0; m < 4; ++m) {
        const s8v* Arow = reinterpret_cast<const s8v*>(&sA[m * 16 + n16][0]);
        #pragma unroll
        for (int s = 0; s < 8; ++s) {
            s8v a = Arow[s * 4 + q];
            acc[m][0] = __builtin_amdgcn_mfma_f32_16x16x32_bf16(a, bfrag[s][0], acc[m][0], 0, 0, 0);
            acc[m][1] = __builtin_amdgcn_mfma_f32_16x16x32_bf16(a, bfrag[s][1], acc[m][1], 0, 0, 0);
        }
    }

    float bj0 = bl[w * 32 + n16];
    float bj1 = bl[w * 32 + 16 + n16];
    #pragma unroll
    for (int m = 0; m < 4; ++m) {
        #pragma unroll
        for (int r = 0; r < 4; ++r) { acc[m][0][r] += bj0; acc[m][1][r] += bj1; }
    }

    #pragma unroll
    for (int m = 0; m < 4; ++m) {
        float p[4];
        #pragma unroll
        for (int r = 0; r < 4; ++r)
            p[r] = acc[m][0][r] * acc[m][0][r] + acc[m][1][r] * acc[m][1][r];
        #pragma unroll
        for (int off = 1; off <= 8; off <<= 1) {
            #pragma unroll
            for (int r = 0; r < 4; ++r) p[r] += __shfl_xor(p[r], off, 64);
        }
        if (n16 == 0) {
            #pragma unroll
            for (int r = 0; r < 4; ++r) sNorm[w][m * 16 + q * 4 + r] = p[r];
        }
    }
    __syncthreads();

    #pragma unroll
    for (int m = 0; m < 4; ++m) {
        #pragma unroll
        for (int r = 0; r < 4; ++r) {
            int node = m * 16 + q * 4 + r;
            float tot = sNorm[0][node] + sNorm[1][node] + sNorm[2][node] + sNorm[3][node];
            float scl = 1.0f / fmaxf(sqrtf(tot), 1e-12f);
            sA[node][w * 32 + n16]      = f2bf(fmaxf(acc[m][0][r] * scl, 0.0f));
            sA[node][w * 32 + 16 + n16] = f2bf(fmaxf(acc[m][1][r] * scl, 0.0f));
        }
    }

    s8v ufrag[4][4];
    float ubj[4];
    #pragma unroll
    for (int j = 0; j < 4; ++j) {
        int col = w * 64 + j * 16 + n16;
        const s8v* Brow = reinterpret_cast<const s8v*>(Wuv + (size_t)col * 128);
        #pragma unroll
        for (int s = 0; s < 4; ++s) ufrag[j][s] = Brow[s * 4 + q];
        ubj[j] = (col < 128) ? lpb1[col] : 0.0f;
    }
    __syncthreads();

    #pragma unroll
    for (int m = 0; m < 4; ++m) {
        f4v ua[4];
        #pragma unroll
        for (int j = 0; j < 4; ++j) ua[j] = f4v{0.0f, 0.0f, 0.0f, 0.0f};
        const s8v* Arow = reinterpret_cast<const s8v*>(&sA[m * 16 + n16][0]);
        #pragma unroll
        for (int s = 0; s < 4; ++s) {
            s8v a = Arow[s * 4 + q];
            #pragma unroll
            for (int j = 0; j < 4; ++j)
                ua[j] = __builtin_amdgcn_mfma_f32_16x16x32_bf16(a, ufrag[j][s], ua[j], 0, 0, 0);
        }
        #pragma unroll
        for (int r = 0; r < 4; ++r) {
            int n = n0 + m * 16 + q * 4 + r;
            if (n < N) {
                #pragma unroll
                for (int j = 0; j < 4; ++j)
                    uv[(size_t)n * 256 + w * 64 + j * 16 + n16] = f2bf(ua[j][r] + ubj[j]);
            }
        }
    }
}

// ---------------------------------------------------------------------------
// Edge MLP, u-bucket-sorted: grid = NBUCK x QSUB.
// ---------------------------------------------------------------------------
__global__ __launch_bounds__(256) void mlp_sorted_kernel(
    const unsigned short* __restrict__ uv, const unsigned long long* __restrict__ qpacked,
    const int* __restrict__ qcur, const unsigned short* __restrict__ W2b,
    const float* __restrict__ lpb2, const float* __restrict__ lpW3,
    const float* __restrict__ lpb3, float* __restrict__ out)
{
    int b = blockIdx.x >> 3;
    int sub = blockIdx.x & (QSUB - 1);
    int qn = min(qcur[b], QCAP);
    if (qn <= 0) return;
    int qbase = b * QCAP;
    int tiles = (qn + 63) >> 6;

    int t = threadIdx.x;
    int lane = t & 63;
    int w = t >> 6;
    int n16 = lane & 15;
    int q = lane >> 4;
    const uint4* uv4 = reinterpret_cast<const uint4*>(uv);
    float b3 = lpb3[0];

    for (int tile = sub; tile < tiles; tile += QSUB) {
        int k = tile * 64 + w * 16 + n16;
        int kc = min(k, qn - 1);
        unsigned long long p = qpacked[qbase + kc];
        int nr = (int)(p >> 40);
        int nc = (int)((p >> 20) & 0xFFFFFu);
        int eqi = (int)(p & 0xFFFFFu);

        uint4 uu[4], vv[4];
        #pragma unroll
        for (int s = 0; s < 4; ++s) uu[s] = uv4[(size_t)nr * 32 + s * 4 + q];
        #pragma unroll
        for (int s = 0; s < 4; ++s) vv[s] = uv4[(size_t)nc * 32 + 16 + s * 4 + q];

        s8v h[4];
        #pragma unroll
        for (int s = 0; s < 4; ++s) {
            const unsigned int* pu = reinterpret_cast<const unsigned int*>(&uu[s]);
            const unsigned int* pv = reinterpret_cast<const unsigned int*>(&vv[s]);
            union { unsigned int u[4]; s8v v; } tmp;
            #pragma unroll
            for (int d = 0; d < 4; ++d) {
                float lo = fmaxf(bflo(pu[d]) + bflo(pv[d]), 0.0f);
                float hi = fmaxf(bfhi(pu[d]) + bfhi(pv[d]), 0.0f);
                tmp.u[d] = pack2bf(lo, hi);
            }
            h[s] = tmp.v;
        }

        f4v acc[4];
        #pragma unroll
        for (int nt = 0; nt < 4; ++nt) acc[nt] = f4v{0.0f, 0.0f, 0.0f, 0.0f};
        for (int s = 0; s < 4; ++s) {
            #pragma unroll
            for (int nt = 0; nt < 4; ++nt) {
                const s8v* Brow = reinterpret_cast<const s8v*>(W2b + (size_t)(nt * 16 + n16) * 128);
                s8v bfr = Brow[s * 4 + q];
                acc[nt] = __builtin_amdgcn_mfma_f32_16x16x32_bf16(h[s], bfr, acc[nt], 0, 0, 0);
            }
        }

        float part[4] = {0.0f, 0.0f, 0.0f, 0.0f};
        #pragma unroll
        for (int nt = 0; nt < 4; ++nt) {
            float bj = lpb2[nt * 16 + n16];
            float w3 = lpW3[nt * 16 + n16];
            #pragma unroll
            for (int r = 0; r < 4; ++r) {
                float h2 = fmaxf(acc[nt][r] + bj, 0.0f);
                part[r] += h2 * w3;
            }
        }
        #pragma unroll
        for (int off = 1; off <= 8; off <<= 1) {
            #pragma unroll
            for (int r = 0; r < 4; ++r) part[r] += __shfl_xor(part[r], off, 64);
        }
        #pragma unroll
        for (int r = 0; r < 4; ++r) {
            int jj = q * 4 + r;
            int eqr = __shfl(eqi, jj, 16);       // executed by all lanes
            int slot = tile * 64 + w * 16 + jj;
            if (n16 == 0 && slot < qn) {
                float s = part[r] + b3;
                out[eqr] = 1.0f / (1.0f + expf(-s));
            }
        }
    }
}

// ---------------------------------------------------------------------------
// Plain edge MLP (fallback when workspace lacks qpacked room)
// ---------------------------------------------------------------------------
__global__ __launch_bounds__(256) void mlp_kernel(
    const unsigned short* __restrict__ uv, const int* __restrict__ rowI,
    const int* __restrict__ colI, const unsigned short* __restrict__ W2b,
    const float* __restrict__ lpb2, const float* __restrict__ lpW3,
    const float* __restrict__ lpb3, float* __restrict__ out, int EQ)
{
    int t = threadIdx.x;
    int lane = t & 63;
    int w = t >> 6;
    int n16 = lane & 15;
    int q = lane >> 4;
    int e = blockIdx.x * 64 + w * 16 + n16;
    int ec = min(e, EQ - 1);
    int nr = rowI[ec];
    int nc = colI[ec];
    const uint4* uv4 = reinterpret_cast<const uint4*>(uv);

    uint4 uu[4], vv[4];
    #pragma unroll
    for (int s = 0; s < 4; ++s) uu[s] = uv4[(size_t)nr * 32 + s * 4 + q];
    #pragma unroll
    for (int s = 0; s < 4; ++s) vv[s] = uv4[(size_t)nc * 32 + 16 + s * 4 + q];

    s8v h[4];
    #pragma unroll
    for (int s = 0; s < 4; ++s) {
        const unsigned int* pu = reinterpret_cast<const unsigned int*>(&uu[s]);
        const unsigned int* pv = reinterpret_cast<const unsigned int*>(&vv[s]);
        union { unsigned int u[4]; s8v v; } tmp;
        #pragma unroll
        for (int d = 0; d < 4; ++d) {
            float lo = fmaxf(bflo(pu[d]) + bflo(pv[d]), 0.0f);
            float hi = fmaxf(bfhi(pu[d]) + bfhi(pv[d]), 0.0f);
            tmp.u[d] = pack2bf(lo, hi);
        }
        h[s] = tmp.v;
    }

    f4v acc[4];
    #pragma unroll
    for (int nt = 0; nt < 4; ++nt) acc[nt] = f4v{0.0f, 0.0f, 0.0f, 0.0f};
    for (int s = 0; s < 4; ++s) {
        #pragma unroll
        for (int nt = 0; nt < 4; ++nt) {
            const s8v* Brow = reinterpret_cast<const s8v*>(W2b + (size_t)(nt * 16 + n16) * 128);
            s8v b = Brow[s * 4 + q];
            acc[nt] = __builtin_amdgcn_mfma_f32_16x16x32_bf16(h[s], b, acc[nt], 0, 0, 0);
        }
    }

    float part[4] = {0.0f, 0.0f, 0.0f, 0.0f};
    #pragma unroll
    for (int nt = 0; nt < 4; ++nt) {
        float bj = lpb2[nt * 16 + n16];
        float w3 = lpW3[nt * 16 + n16];
        #pragma unroll
        for (int r = 0; r < 4; ++r) {
            float h2 = fmaxf(acc[nt][r] + bj, 0.0f);
            part[r] += h2 * w3;
        }
    }
    #pragma unroll
    for (int off = 1; off <= 8; off <<= 1) {
        #pragma unroll
        for (int r = 0; r < 4; ++r) part[r] += __shfl_xor(part[r], off, 64);
    }
    if (n16 == 0) {
        float b3 = lpb3[0];
        #pragma unroll
        for (int r = 0; r < 4; ++r) {
            int eq = blockIdx.x * 64 + w * 16 + q * 4 + r;
            if (eq < EQ) {
                float s = part[r] + b3;
                out[eq] = 1.0f / (1.0f + expf(-s));
            }
        }
    }
}

// ---------------------------------------------------------------------------
extern "C" void kernel_launch(void* const* d_in, const int* in_sizes, int n_in,
                              void* d_out, int out_size, void* d_ws, size_t ws_size,
                              hipStream_t stream)
{
    const float* x   = (const float*)d_in[0];
    const int*   ei  = (const int*)d_in[1];
    const int*   eiq = (const int*)d_in[2];
    const float* Wl[3] = {(const float*)d_in[3], (const float*)d_in[6], (const float*)d_in[9]};
    const float* bl[3] = {(const float*)d_in[4], (const float*)d_in[7], (const float*)d_in[10]};
    const float* Wr[3] = {(const float*)d_in[5], (const float*)d_in[8], (const float*)d_in[11]};
    const float* lpW1 = (const float*)d_in[12];
    const float* lpb1 = (const float*)d_in[13];
    const float* lpW2 = (const float*)d_in[14];
    const float* lpb2 = (const float*)d_in[15];
    const float* lpW3 = (const float*)d_in[16];
    const float* lpb3 = (const float*)d_in[17];

    int N  = in_sizes[0] / D;
    int E  = in_sizes[1] / 2;
    int EQ = in_sizes[2] / 2;

    // ---- workspace layout (unchanged) ----
    int* cnt    = (int*)d_ws;                    // N
    int* cursor = cnt + N;                       // NBUCK (relative counts)
    int* qcur   = cursor + NBUCK;                // NBUCK
    int* ell    = qcur + NBUCK;                  // N * 64
    size_t intWords = (size_t)N + 2 * NBUCK + (size_t)N * 64;
    intWords = (intWords + 15) & ~(size_t)15;
    size_t nd = (size_t)N * D;
    unsigned short* bufA = (unsigned short*)((int*)d_ws + intWords);
    unsigned short* bufB = bufA + nd;
    unsigned short* bufC = bufB + nd;
    unsigned int* f8a = (unsigned int*)(bufC + nd);   // nd/4 uints each
    unsigned int* f8b = f8a + nd / 4;
    unsigned int* f8c = f8b + nd / 4;
    unsigned long long* packed = (unsigned long long*)(f8c + nd / 4);
    unsigned short* Wc  = (unsigned short*)(packed + (size_t)NBUCK * BCAP);
    unsigned short* Wuv = Wc + 98304;
    unsigned short* W2b = Wuv + 32768;
    size_t qoff = (size_t)((char*)(W2b + 8192) - (char*)d_ws);
    qoff = (qoff + 7) & ~(size_t)7;
    unsigned long long* qpacked = (unsigned long long*)((char*)d_ws + qoff);
    size_t needQ = qoff + (size_t)NBUCK * QCAP * 8;
    int doQ = (ws_size >= needQ) ? 1 : 0;
    unsigned short* uvb = (unsigned short*)f8a;       // overlay

    const int* src = ei;
    const int* dst = ei + E;

    // ---- one memset for all counters, then the mega-prep dispatch ----
    hipMemsetAsync(cnt, 0, ((size_t)N + 2 * NBUCK) * sizeof(int), stream);
    int n4 = (int)(nd / 4);
    int binB   = (E + EPB - 1) / EPB;
    int convxB = (n4 + 255) / 256;
    int convwB = (139264 + 255) / 256;
    int qB     = doQ ? (EQ + EPBQ - 1) / EPBQ : 0;
    int prepGrid = binB + convxB + convwB + qB;
    prep_kernel<<<prepGrid, 256, 0, stream>>>(
        src, dst, cursor, packed, E, binB,
        x, bufA, f8a, n4, convxB,
        Wl[0], Wr[0], Wl[1], Wr[1], Wl[2], Wr[2], lpW1, lpW2, Wc, Wuv, W2b, convwB,
        eiq, eiq + EQ, qcur, qpacked, EQ);
    ell_build_kernel<<<NBUCK * 4, 256, 0, stream>>>(packed, cursor, cnt, ell, N);

    // ---- 3 SAGE layers: gather + GEMM (fp8 emitted in GEMM epilogue) ----
    int mBlocks = (N + 63) / 64;
    gather_mean_kernel<<<mBlocks, 256, 0, stream>>>(
        (const uint2*)f8a, cnt, ell, bufB, N);
    sage_gemm_kernel<<<mBlocks, 256, 0, stream>>>(
        bufA, bufB, Wc, bl[0], bufB, (unsigned short*)f8b, N);

    gather_mean_kernel<<<mBlocks, 256, 0, stream>>>(
        (const uint2*)f8b, cnt, ell, bufC, N);
    sage_gemm_kernel<<<mBlocks, 256, 0, stream>>>(
        bufB, bufC, Wc + 32768, bl[1], bufC, (unsigned short*)f8c, N);

    gather_mean_kernel<<<mBlocks, 256, 0, stream>>>(
        (const uint2*)f8c, cnt, ell, bufA, N);
    sage_gemm_uv_kernel<<<mBlocks, 256, 0, stream>>>(
        bufC, bufA, Wc + 65536, bl[2], Wuv, lpb1, uvb, N);

    // ---- edge MLP ----
    if (doQ) {
        mlp_sorted_kernel<<<NBUCK * QSUB, 256, 0, stream>>>(
            uvb, qpacked, qcur, W2b, lpb2, lpW3, lpb3, (float*)d_out);
    } else {
        mlp_kernel<<<(EQ + 63) / 64, 256, 0, stream>>>(
            uvb, eiq, eiq + EQ, W2b, lpb2, lpW3, lpb3, (float*)d_out, EQ);
    }
}